// Round 9
// baseline (175.447 us; speedup 1.0000x reference)
//
#include <hip/hip_runtime.h>
#include <float.h>

#define Bb 2
#define Ll 256
#define Ss 384
#define Hh 768
#define Tc 16
#define Dc 50
#define WD 100
#define CV 128
#define NG 200     // 4*Dc gates
#define OUTC 968   // H + WD + 2*Dc

// ws layout (floats):
//   [0, 128)    minv partials
//   [128, ...)  xproj table [2][128][200], bias folded in

__device__ inline float tanh_fast(float x) {
    float e = __expf(2.f * x);
    return 1.f - 2.f / (e + 1.f);
}
__device__ inline float sigmoid_fast(float x) {
    return 1.f / (1.f + __expf(-x));
}

// ================= kernel 1: min partials | xproj | embed =================
// grid 256: [0,128) min, [128,192) xproj (dir*32 + cid-chunk of 4), [192,256) embed

__global__ __launch_bounds__(256) void prep_kernel(
        const float* __restrict__ bert, const float* __restrict__ char_table,
        const float* __restrict__ Wih_f, const float* __restrict__ bih_f, const float* __restrict__ bhh_f,
        const float* __restrict__ Wih_b, const float* __restrict__ bih_b, const float* __restrict__ bhh_b,
        const int* __restrict__ word_ids, const float* __restrict__ word_table,
        float* __restrict__ minp, float* __restrict__ xpt, float* __restrict__ out) {
    int blk = blockIdx.x, tid = threadIdx.x;
    if (blk < 128) {
        const int n4 = (Bb * Ss * Hh) / 4;       // 147456 float4
        const float4* b4 = (const float4*)bert;
        float m = FLT_MAX;
        for (int i = blk * 256 + tid; i < n4; i += 128 * 256) {
            float4 v = b4[i];
            m = fminf(m, fminf(fminf(v.x, v.y), fminf(v.z, v.w)));
        }
        #pragma unroll
        for (int off = 32; off; off >>= 1) m = fminf(m, __shfl_down(m, off, 64));
        __shared__ float red[4];
        if ((tid & 63) == 0) red[tid >> 6] = m;
        __syncthreads();
        if (tid == 0) minp[blk] = fminf(fminf(red[0], red[1]), fminf(red[2], red[3]));
    } else if (blk < 192) {
        int idx = blk - 128;            // dir*32 + cid-chunk
        int dir = idx >> 5, c0 = (idx & 31) * 4;
        const float* Wih = dir ? Wih_b : Wih_f;
        const float* bih = dir ? bih_b : bih_f;
        const float* bhh = dir ? bhh_b : bhh_f;
        __shared__ float ct[4][Dc];
        if (tid < 4 * Dc) ((float*)ct)[tid] = char_table[c0 * Dc + tid];
        __syncthreads();
        if (tid < NG) {
            float w[Dc];
            #pragma unroll
            for (int j = 0; j < Dc; j++) w[j] = Wih[tid * Dc + j];
            float bias = bih[tid] + bhh[tid];
            #pragma unroll
            for (int cid = 0; cid < 4; cid++) {
                float a = bias;
                #pragma unroll
                for (int j = 0; j < Dc; j++) a += w[j] * ct[cid][j];
                xpt[(dir * CV + c0 + cid) * NG + tid] = a;   // coalesced
            }
        }
    } else {
        for (int i = (blk - 192) * 256 + tid; i < Bb * Ll * WD; i += 64 * 256) {
            int bl = i / WD, d = i - bl * WD;
            out[(size_t)bl * OUTC + Hh + d] = word_table[(size_t)word_ids[bl] * WD + d];
        }
    }
}

// ================= kernel 2: word_reps | char bi-LSTM (fused, 512 threads) =================
// grid 512: [0,384) word: (b, l-tile of 8, h-chunk of 128 floats), 8 waves x 48 s
//           [384,512) lstm: 8 independent (chain,dir) waves per block, lockstep barriers

__global__ __launch_bounds__(512, 2) void fused_kernel(
        const float* __restrict__ bert, const int* __restrict__ p2w,
        const float* __restrict__ minp,
        const int* __restrict__ char_ids, const int* __restrict__ char_count,
        const float* __restrict__ Whh_f, const float* __restrict__ Whh_b,
        const float* __restrict__ xpt, float* __restrict__ out) {
    __shared__ __align__(16) char smem[32896];
    int blk = blockIdx.x, tid = threadIdx.x;
    int wv = tid >> 6, lane = tid & 63;

    if (blk < 384) {
        // ---------------- word_reps masked max ----------------
        float (*sacc)[8][128] = (float (*)[8][128])smem;   // 8 waves * 8 rows * 128 = 32 KB
        float* sminv = (float*)(smem + 32768);

        if (tid < 64) {
            float m = fminf(minp[tid], minp[tid + 64]);
            #pragma unroll
            for (int off = 32; off; off >>= 1) m = fminf(m, __shfl_down(m, off, 64));
            if (tid == 0) *sminv = m;
        }
        int hc = blk % 6;              // h-chunk of 128 floats
        int lt = (blk / 6) & 31;       // l-tile of 8
        int b  = blk / 192;
        int l0 = lt * 8;
        int s0 = wv * 48;

        // 48-bit row masks via ballot -> 2 SGPRs per row
        const int* pm = p2w + ((size_t)(b * Ll + l0)) * Ss + s0;
        unsigned mlo[8], mhi[8];
        #pragma unroll
        for (int r = 0; r < 8; r++) {
            unsigned long long bal = __ballot(lane < 48 ? (pm[r * Ss + lane] != 0) : false);
            mlo[r] = __builtin_amdgcn_readfirstlane((unsigned)bal);
            mhi[r] = __builtin_amdgcn_readfirstlane((unsigned)(bal >> 32));
        }

        const float2* bb2 = (const float2*)(bert + (size_t)b * Ss * Hh) + hc * 64 + lane;
        float2 acc[8];
        #pragma unroll
        for (int r = 0; r < 8; r++) { acc[r].x = -FLT_MAX; acc[r].y = -FLT_MAX; }

        for (int jo = 0; jo < 48; jo += 8) {        // 8 loads in flight
            float2 v[8];
            #pragma unroll
            for (int k = 0; k < 8; k++) v[k] = bb2[(size_t)(s0 + jo + k) * 384];
            #pragma unroll
            for (int k = 0; k < 8; k++) {
                int j = jo + k;
                #pragma unroll
                for (int r = 0; r < 8; r++) {
                    unsigned bit = (j < 32 ? mlo[r] >> j : mhi[r] >> (j - 32)) & 1u;
                    if (bit) {                       // wave-uniform scalar branch
                        acc[r].x = fmaxf(acc[r].x, v[k].x);
                        acc[r].y = fmaxf(acc[r].y, v[k].y);
                    }
                }
            }
        }
        #pragma unroll
        for (int r = 0; r < 8; r++)
            *(float2*)&sacc[wv][r][lane * 2] = acc[r];
        __syncthreads();

        float mv = *sminv;
        #pragma unroll
        for (int e = tid; e < 8 * 128; e += 512) {   // 2 iterations
            int r = e >> 7, cx = e & 127;
            float m = sacc[0][r][cx];
            #pragma unroll
            for (int k = 1; k < 8; k++) m = fmaxf(m, sacc[k][r][cx]);
            if (m == -FLT_MAX) m = mv;               // fully-masked row -> global min fill
            out[((size_t)(b * Ll + l0 + r)) * OUTC + hc * 128 + cx] = m;
        }
    } else {
        // ---------------- char bi-LSTM: one wave per (chain, dir) ----------------
        float (*hs)[52] = (float (*)[52])smem;       // per-wave h slice (row = 208B, 16B-aligned)
        float* hsw = hs[wv];

        int wid = (blk - 384) * 8 + wv;              // 0..1023
        int n = wid >> 1, dir = wid & 1;
        const float* Whh = dir ? Whh_b : Whh_f;

        int len = char_count[n];
        if (len < 1) len = 1;

        // lane t<16 holds scid[t], reversal folded for backward direction
        int cidv = 0;
        if (lane < Tc) {
            int st = dir ? (lane < len ? len - 1 - lane : lane) : lane;
            cidv = char_ids[n * Tc + st];
        }

        // recurrent weights into registers: w[q][0..49], zero-padded to 52
        float w[4][52];
        if (lane < Dc) {
            #pragma unroll
            for (int q = 0; q < 4; q++) {
                const float2* wr = (const float2*)(Whh + (q * Dc + lane) * Dc);
                #pragma unroll
                for (int m = 0; m < 25; m++) {
                    float2 t = wr[m];
                    w[q][2 * m] = t.x; w[q][2 * m + 1] = t.y;
                }
            }
        }
        #pragma unroll
        for (int q = 0; q < 4; q++) { w[q][50] = 0.f; w[q][51] = 0.f; }

        if (lane < 52) hsw[lane] = 0.f;
        __syncthreads();

        // prefetch xproj row for t=0
        int cid0 = __shfl(cidv, 0);
        const float* xr = xpt + (size_t)(dir * CV + cid0) * NG;
        float xp[4];
        #pragma unroll
        for (int q = 0; q < 4; q++) xp[q] = (lane < Dc) ? xr[q * Dc + lane] : 0.f;

        float c = 0.f, h = 0.f, maxv = -FLT_MAX;
        for (int t = 0; t < Tc; t++) {
            // prefetch next step's xproj (overlaps the gemv)
            int tn = (t + 1 < Tc) ? t + 1 : t;
            int cidn = __shfl(cidv, tn);
            const float* xrn = xpt + (size_t)(dir * CV + cidn) * NG;
            float xpn[4];
            #pragma unroll
            for (int q = 0; q < 4; q++) xpn[q] = (lane < Dc) ? xrn[q * Dc + lane] : 0.f;

            float g0 = xp[0], g1 = xp[1], g2 = xp[2], g3 = xp[3];
            #pragma unroll
            for (int m = 0; m < 13; m++) {
                float4 hv = *(const float4*)&hsw[4 * m];
                g0 += hv.x * w[0][4*m] + hv.y * w[0][4*m+1] + hv.z * w[0][4*m+2] + hv.w * w[0][4*m+3];
                g1 += hv.x * w[1][4*m] + hv.y * w[1][4*m+1] + hv.z * w[1][4*m+2] + hv.w * w[1][4*m+3];
                g2 += hv.x * w[2][4*m] + hv.y * w[2][4*m+1] + hv.z * w[2][4*m+2] + hv.w * w[2][4*m+3];
                g3 += hv.x * w[3][4*m] + hv.y * w[3][4*m+1] + hv.z * w[3][4*m+2] + hv.w * w[3][4*m+3];
            }
            if (lane < Dc) {
                float si = sigmoid_fast(g0);
                float sf = sigmoid_fast(g1);
                float tg = tanh_fast(g2);
                float so = sigmoid_fast(g3);
                c = sf * c + si * tg;
                h = so * tanh_fast(c);
                if (t < len) maxv = fmaxf(maxv, h);   // ragged max (scan order == valid region)
            }
            __syncthreads();                          // lockstep: old hs reads done
            if (lane < Dc) hsw[lane] = h;
            __syncthreads();                          // write visible before next gemv
            #pragma unroll
            for (int q = 0; q < 4; q++) xp[q] = xpn[q];
        }
        if (lane < Dc)
            out[(size_t)n * OUTC + (Hh + WD) + dir * Dc + lane] = maxv;
    }
}

extern "C" void kernel_launch(void* const* d_in, const int* in_sizes, int n_in,
                              void* d_out, int out_size, void* d_ws, size_t ws_size,
                              hipStream_t stream) {
    const float* bert       = (const float*)d_in[0];
    const int*   p2w        = (const int*)d_in[1];
    const int*   word_ids   = (const int*)d_in[2];
    const int*   char_count = (const int*)d_in[3];
    const int*   char_ids   = (const int*)d_in[4];
    // d_in[5] token_masks_char: consistent with char_count, unused
    const float* word_table = (const float*)d_in[6];
    const float* char_table = (const float*)d_in[7];
    const float* Wih_f = (const float*)d_in[8];
    const float* Whh_f = (const float*)d_in[9];
    const float* bih_f = (const float*)d_in[10];
    const float* bhh_f = (const float*)d_in[11];
    const float* Wih_b = (const float*)d_in[12];
    const float* Whh_b = (const float*)d_in[13];
    const float* bih_b = (const float*)d_in[14];
    const float* bhh_b = (const float*)d_in[15];
    float* out = (float*)d_out;

    float* minp = (float*)d_ws;          // 128 floats
    float* xpt  = minp + 128;            // 2*128*200 floats

    prep_kernel<<<256, 256, 0, stream>>>(
        bert, char_table, Wih_f, bih_f, bhh_f, Wih_b, bih_b, bhh_b,
        word_ids, word_table, minp, xpt, out);
    fused_kernel<<<512, 512, 0, stream>>>(
        bert, p2w, minp, char_ids, char_count, Whh_f, Whh_b, xpt, out);
}

// Round 10
// 128.457 us; speedup vs baseline: 1.3658x; 1.3658x over previous
//
#include <hip/hip_runtime.h>
#include <float.h>

#define Bb 2
#define Ll 256
#define Ss 384
#define Hh 768
#define Tc 16
#define Dc 50
#define WD 100
#define CV 128
#define NG 200     // 4*Dc gates
#define OUTC 968   // H + WD + 2*Dc
#define LT 8       // l rows per word block
#define TOT (Bb * Ll * Hh)   // 393216

// ws layout (floats):
//   [0, 128)        minv partials
//   [128, 51328)    xproj table [2][128][200], bias folded in
//   [51328, ...)    word partials [4][B*L][Hh]  (6 MB)

__device__ inline float tanh_fast(float x) {
    float e = __expf(2.f * x);
    return 1.f - 2.f / (e + 1.f);
}
__device__ inline float sigmoid_fast(float x) {
    return 1.f / (1.f + __expf(-x));
}

// ================= kernel A: min | xproj | embed | word partials =================
// grid 1792: [0,128) min, [128,192) xproj, [192,256) embed, [256,1792) word

__global__ __launch_bounds__(256) void kernelA(
        const float* __restrict__ bert, const int* __restrict__ p2w,
        const float* __restrict__ char_table,
        const float* __restrict__ Wih_f, const float* __restrict__ bih_f, const float* __restrict__ bhh_f,
        const float* __restrict__ Wih_b, const float* __restrict__ bih_b, const float* __restrict__ bhh_b,
        const int* __restrict__ word_ids, const float* __restrict__ word_table,
        float* __restrict__ minp, float* __restrict__ xpt, float* __restrict__ partial,
        float* __restrict__ out) {
    int blk = blockIdx.x, tid = threadIdx.x;
    if (blk < 128) {
        const int n4 = (Bb * Ss * Hh) / 4;       // 147456 float4
        const float4* b4 = (const float4*)bert;
        float m = FLT_MAX;
        for (int i = blk * 256 + tid; i < n4; i += 128 * 256) {
            float4 v = b4[i];
            m = fminf(m, fminf(fminf(v.x, v.y), fminf(v.z, v.w)));
        }
        #pragma unroll
        for (int off = 32; off; off >>= 1) m = fminf(m, __shfl_down(m, off, 64));
        __shared__ float red[4];
        if ((tid & 63) == 0) red[tid >> 6] = m;
        __syncthreads();
        if (tid == 0) minp[blk] = fminf(fminf(red[0], red[1]), fminf(red[2], red[3]));
    } else if (blk < 192) {
        int idx = blk - 128;            // dir*32 + cid-chunk of 4
        int dir = idx >> 5, c0 = (idx & 31) * 4;
        const float* Wih = dir ? Wih_b : Wih_f;
        const float* bih = dir ? bih_b : bih_f;
        const float* bhh = dir ? bhh_b : bhh_f;
        __shared__ float ct[4][Dc];
        if (tid < 4 * Dc) ((float*)ct)[tid] = char_table[c0 * Dc + tid];
        __syncthreads();
        if (tid < NG) {
            float w[Dc];
            #pragma unroll
            for (int j = 0; j < Dc; j++) w[j] = Wih[tid * Dc + j];
            float bias = bih[tid] + bhh[tid];
            #pragma unroll
            for (int cid = 0; cid < 4; cid++) {
                float a = bias;
                #pragma unroll
                for (int j = 0; j < Dc; j++) a += w[j] * ct[cid][j];
                xpt[(dir * CV + c0 + cid) * NG + tid] = a;   // coalesced
            }
        }
    } else if (blk < 256) {
        for (int i = (blk - 192) * 256 + tid; i < Bb * Ll * WD; i += 64 * 256) {
            int bl = i / WD, d = i - bl * WD;
            out[(size_t)bl * OUTC + Hh + d] = word_table[(size_t)word_ids[bl] * WD + d];
        }
    } else {
        // ---- word partial: block = (b, sc, lt, hc); wave owns 24 s ----
        int idx = blk - 256;           // 0..1535
        int hc  = idx % 6;             // h-chunk of 128 floats
        int lt  = (idx / 6) & 31;      // l-tile of 8
        int bsc = idx / 192;           // b*4 + sc
        int b   = bsc >> 2, sc = bsc & 3;
        int w    = tid >> 6;           // wave -> 24-s slice
        int lane = tid & 63;
        int s0 = sc * 96 + w * 24;

        // per-row 24-bit masks via ballot -> SGPRs (no mask traffic in the loop)
        const int* pm = p2w + ((size_t)(b * Ll + lt * LT)) * Ss + s0;
        unsigned m[LT];
        #pragma unroll
        for (int r = 0; r < LT; r++) {
            int v = (lane < 24) ? pm[r * Ss + lane] : 0;
            unsigned long long bal = __ballot(v != 0);
            m[r] = __builtin_amdgcn_readfirstlane((unsigned)bal);
        }

        const float2* bb2 = (const float2*)(bert + (size_t)b * Ss * Hh) + hc * 64 + lane;
        float2 acc[LT];
        #pragma unroll
        for (int r = 0; r < LT; r++) { acc[r].x = -FLT_MAX; acc[r].y = -FLT_MAX; }

        #pragma unroll
        for (int j = 0; j < 24; j++) {
            float2 v = bb2[(size_t)(s0 + j) * 384];
            #pragma unroll
            for (int r = 0; r < LT; r++) {
                if (m[r] & (1u << j)) {          // scalar (wave-uniform) branch
                    acc[r].x = fmaxf(acc[r].x, v.x);
                    acc[r].y = fmaxf(acc[r].y, v.y);
                }
            }
        }

        __shared__ float sacc[4][LT][128];
        #pragma unroll
        for (int r = 0; r < LT; r++)
            *(float2*)&sacc[w][r][lane * 2] = acc[r];
        __syncthreads();

        for (int e = tid; e < LT * 128; e += 256) {
            int r = e >> 7, c = e & 127;
            float m0 = fmaxf(fmaxf(sacc[0][r][c], sacc[1][r][c]),
                             fmaxf(sacc[2][r][c], sacc[3][r][c]));
            size_t row = (size_t)b * Ll + lt * LT + r;
            partial[((size_t)sc * (Bb * Ll) + row) * Hh + hc * 128 + c] = m0;
        }
    }
}

// ================= kernel B: LSTM (4 indep waves/block) | word finalize =================
// grid 640: [0,256) lstm, [256,640) finalize

__global__ __launch_bounds__(256, 1) void kernelB(
        const int* __restrict__ char_ids, const int* __restrict__ char_count,
        const float* __restrict__ Whh_f, const float* __restrict__ Whh_b,
        const float* __restrict__ xpt, const float* __restrict__ partial,
        const float* __restrict__ minp, float* __restrict__ out) {
    int blk = blockIdx.x, tid = threadIdx.x;
    int wv = tid >> 6, lane = tid & 63;

    if (blk < 256) {
        // ---------------- char bi-LSTM: one wave per (chain, dir), no barriers ----------------
        __shared__ __align__(16) float hs[4][52];    // per-wave private slice (208 B rows)
        float* hsw = hs[wv];

        int wid = blk * 4 + wv;                      // 0..1023
        int n = wid >> 1, dir = wid & 1;
        const float* Whh = dir ? Whh_b : Whh_f;

        int len = char_count[n];
        if (len < 1) len = 1;

        // lane t<16 holds scid[t], reversal folded for backward direction
        int cidv = 0;
        if (lane < Tc) {
            int st = dir ? (lane < len ? len - 1 - lane : lane) : lane;
            cidv = char_ids[n * Tc + st];
        }

        // recurrent weights into registers: w[q][0..49], zero-padded to 52
        float w[4][52];
        if (lane < Dc) {
            #pragma unroll
            for (int q = 0; q < 4; q++) {
                const float2* wr = (const float2*)(Whh + (q * Dc + lane) * Dc);
                #pragma unroll
                for (int mm = 0; mm < 25; mm++) {
                    float2 t = wr[mm];
                    w[q][2 * mm] = t.x; w[q][2 * mm + 1] = t.y;
                }
            }
        }
        #pragma unroll
        for (int q = 0; q < 4; q++) { w[q][50] = 0.f; w[q][51] = 0.f; }

        if (lane < 52) hsw[lane] = 0.f;              // own-wave write; lgkmcnt orders reads

        // prefetch xproj row for t=0
        int cid0 = __shfl(cidv, 0);
        const float* xr = xpt + (size_t)(dir * CV + cid0) * NG;
        float xp[4];
        #pragma unroll
        for (int q = 0; q < 4; q++) xp[q] = (lane < Dc) ? xr[q * Dc + lane] : 0.f;

        float c = 0.f, h = 0.f, maxv = -FLT_MAX;
        for (int t = 0; t < Tc; t++) {
            // prefetch next step's xproj (overlaps the gemv)
            int tn = (t + 1 < Tc) ? t + 1 : t;
            int cidn = __shfl(cidv, tn);
            const float* xrn = xpt + (size_t)(dir * CV + cidn) * NG;
            float xpn[4];
            #pragma unroll
            for (int q = 0; q < 4; q++) xpn[q] = (lane < Dc) ? xrn[q * Dc + lane] : 0.f;

            // gates: g[q] = xp[q] + Whh[q*50+lane,:] . h  (h broadcast from own LDS slice)
            float g0 = xp[0], g1 = xp[1], g2 = xp[2], g3 = xp[3];
            #pragma unroll
            for (int mm = 0; mm < 13; mm++) {
                float4 hv = *(const float4*)&hsw[4 * mm];
                g0 += hv.x * w[0][4*mm] + hv.y * w[0][4*mm+1] + hv.z * w[0][4*mm+2] + hv.w * w[0][4*mm+3];
                g1 += hv.x * w[1][4*mm] + hv.y * w[1][4*mm+1] + hv.z * w[1][4*mm+2] + hv.w * w[1][4*mm+3];
                g2 += hv.x * w[2][4*mm] + hv.y * w[2][4*mm+1] + hv.z * w[2][4*mm+2] + hv.w * w[2][4*mm+3];
                g3 += hv.x * w[3][4*mm] + hv.y * w[3][4*mm+1] + hv.z * w[3][4*mm+2] + hv.w * w[3][4*mm+3];
            }
            if (lane < Dc) {
                float si = sigmoid_fast(g0);
                float sf = sigmoid_fast(g1);
                float tg = tanh_fast(g2);
                float so = sigmoid_fast(g3);
                c = sf * c + si * tg;
                h = so * tanh_fast(c);
                if (t < len) maxv = fmaxf(maxv, h);   // ragged max (scan order == valid region)
                hsw[lane] = h;                        // own-wave LDS; ordered by lgkmcnt
            }
            #pragma unroll
            for (int q = 0; q < 4; q++) xp[q] = xpn[q];
        }
        if (lane < Dc)
            out[(size_t)n * OUTC + (Hh + WD) + dir * Dc + lane] = maxv;
    } else {
        // ---------------- finalize word_reps: reduce 4 s-chunk partials + minv fill ----------------
        __shared__ float sminv;
        if (tid < 64) {
            float m = fminf(minp[tid], minp[tid + 64]);
            #pragma unroll
            for (int off = 32; off; off >>= 1) m = fminf(m, __shfl_down(m, off, 64));
            if (tid == 0) sminv = m;
        }
        __syncthreads();
        float mv = sminv;
        int e = (blk - 256) * 1024 + tid;
        #pragma unroll
        for (int k = 0; k < 4; k++, e += 256) {
            float m = fmaxf(fmaxf(partial[e], partial[TOT + e]),
                            fmaxf(partial[2 * TOT + e], partial[3 * TOT + e]));
            if (m == -FLT_MAX) m = mv;       // fully-masked row -> global min fill
            int row = e / Hh, c = e - row * Hh;
            out[(size_t)row * OUTC + c] = m;
        }
    }
}

extern "C" void kernel_launch(void* const* d_in, const int* in_sizes, int n_in,
                              void* d_out, int out_size, void* d_ws, size_t ws_size,
                              hipStream_t stream) {
    const float* bert       = (const float*)d_in[0];
    const int*   p2w        = (const int*)d_in[1];
    const int*   word_ids   = (const int*)d_in[2];
    const int*   char_count = (const int*)d_in[3];
    const int*   char_ids   = (const int*)d_in[4];
    // d_in[5] token_masks_char: consistent with char_count, unused
    const float* word_table = (const float*)d_in[6];
    const float* char_table = (const float*)d_in[7];
    const float* Wih_f = (const float*)d_in[8];
    const float* Whh_f = (const float*)d_in[9];
    const float* bih_f = (const float*)d_in[10];
    const float* bhh_f = (const float*)d_in[11];
    const float* Wih_b = (const float*)d_in[12];
    const float* Whh_b = (const float*)d_in[13];
    const float* bih_b = (const float*)d_in[14];
    const float* bhh_b = (const float*)d_in[15];
    float* out = (float*)d_out;

    float* minp    = (float*)d_ws;               // 128 floats
    float* xpt     = minp + 128;                 // 2*128*200 floats
    float* partial = xpt + 2 * CV * NG;          // 4*512*768 floats

    kernelA<<<1792, 256, 0, stream>>>(
        bert, p2w, char_table, Wih_f, bih_f, bhh_f, Wih_b, bih_b, bhh_b,
        word_ids, word_table, minp, xpt, partial, out);
    kernelB<<<640, 256, 0, stream>>>(
        char_ids, char_count, Whh_f, Whh_b, xpt, partial, minp, out);
}